// Round 8
// baseline (639.749 us; speedup 1.0000x reference)
//
#include <hip/hip_runtime.h>

#define D_IN 150528
#define FEAT 256
#define HID 64
#define T 4
#define B 8
#define NROWS 1280            // 5 * 256 rows (W1 + 4x dW1)
#define D4 37632              // D_IN / 4 float4 per row
#define KS 21                 // K splits
#define TILES 7               // 256-float4 tiles per chunk (21*7*256 = 37632)
#define RPW 4                 // rows per wave
#define RPB 16                // rows per block (4 waves)
#define NRB 80                // 1280 / 16

// ---------------- stage 1: the 5 batched GEMVs over K=150528 ----------------
// grid (21, 80), block 256 = 4 waves, no LDS/barriers. Each wave owns 4 rows.
// Per 256-float4 tile: rows processed in PAIRS, each row loaded as 4
// back-to-back 1KB wave-loads (4KB contiguous burst) to raise DRAM page-hit
// rate (the r7 limiter: 1KB interleaved requests across ~64 streams/CU).
// x read from global (L1-hot 16KB window), reused across the row pair.
__global__ __launch_bounds__(256, 4) void stage1(
    const float* __restrict__ x, const float* __restrict__ W1,
    const float* __restrict__ dW1, float* __restrict__ partial) {
  const int ks   = blockIdx.x;                        // 0..20
  const int rb   = blockIdx.y;                        // 0..79
  const int wid  = threadIdx.x >> 6;                  // wave 0..3
  const int lane = threadIdx.x & 63;
  const int r0   = rb * RPB + wid * RPW;              // this wave's 4 rows
  const int kb4  = ks * (TILES * 256);                // float4 offset in K

  const float4* rp[RPW];
#pragma unroll
  for (int i = 0; i < RPW; ++i) {
    int r = r0 + i, m = r >> 8, f = r & 255;
    const float* base = (m == 0) ? (W1 + (size_t)f * D_IN)
                                 : (dW1 + ((size_t)(m - 1) * FEAT + f) * D_IN);
    rp[i] = (const float4*)base + kb4;
  }
  const float4* x4 = (const float4*)x + kb4;          // + b*D4 + idx

  float acc[RPW][B];
#pragma unroll
  for (int i = 0; i < RPW; ++i)
#pragma unroll
    for (int b = 0; b < B; ++b) acc[i][b] = 0.f;

  for (int tile = 0; tile < TILES; ++tile) {
    const int base = tile * 256;                      // float4 idx in chunk
#pragma unroll
    for (int pr = 0; pr < RPW / 2; ++pr) {
      float4 mv[2][4];                                // 2 rows x 4KB bursts
#pragma unroll
      for (int i = 0; i < 2; ++i)
#pragma unroll
        for (int k = 0; k < 4; ++k)
          mv[i][k] = rp[pr * 2 + i][base + k * 64 + lane];
#pragma unroll
      for (int b = 0; b < B; ++b) {
        float4 xv[4];
#pragma unroll
        for (int k = 0; k < 4; ++k)
          xv[k] = x4[(size_t)b * D4 + base + k * 64 + lane];
#pragma unroll
        for (int i = 0; i < 2; ++i)
#pragma unroll
          for (int k = 0; k < 4; ++k)
            acc[pr * 2 + i][b] += mv[i][k].x * xv[k].x + mv[i][k].y * xv[k].y +
                                  mv[i][k].z * xv[k].z + mv[i][k].w * xv[k].w;
      }
    }
  }

  // full-wave butterfly per (i,b); lane k (k<32) keeps pair (k>>3, k&7)
  float outv = 0.f;
#pragma unroll
  for (int i = 0; i < RPW; ++i)
#pragma unroll
    for (int b = 0; b < B; ++b) {
      float v = acc[i][b];
      v += __shfl_xor(v, 1);
      v += __shfl_xor(v, 2);
      v += __shfl_xor(v, 4);
      v += __shfl_xor(v, 8);
      v += __shfl_xor(v, 16);
      v += __shfl_xor(v, 32);
      if (lane == i * B + b) outv = v;                // compile-time acc index
    }
  if (lane < RPW * B)                                 // 32 consecutive floats
    partial[((size_t)ks * NROWS + r0) * B + lane] = outv;
}

// ---------------- stage 2: reduce K-splits, add biases ----------------
__global__ __launch_bounds__(256) void stage2(
    const float* __restrict__ partial, const float* __restrict__ b1,
    const float* __restrict__ db1, float* __restrict__ hp) {
  int idx = blockIdx.x * 256 + threadIdx.x;           // 0..10239
  int r = idx >> 3, b = idx & 7;
  int m = r >> 8, f = r & 255;
  float s = (m == 0) ? b1[f] : db1[(m - 1) * FEAT + f];
  for (int ks = 0; ks < KS; ++ks)
    s += partial[((size_t)ks * NROWS + r) * B + b];
  hp[idx] = s;                                        // hp[r][b]
}

// ---------------- stage 3: everything after hpre, one block per batch ------
__global__ __launch_bounds__(256) void stage3(
    const float* __restrict__ hp, const float* __restrict__ W2,
    const float* __restrict__ b2, const float* __restrict__ mW1,
    const float* __restrict__ mb1, const float* __restrict__ mW2,
    const float* __restrict__ mb2, const float* __restrict__ dW2,
    const float* __restrict__ db2, float* __restrict__ out) {
  __shared__ float h_l[FEAT];
  __shared__ float base_l[FEAT];
  __shared__ float u_l[FEAT];
  __shared__ float mid_l[HID];
  __shared__ float c_l[T];
  const int b = blockIdx.x;                           // batch
  const int g = threadIdx.x;                          // feature

  const float hpre = hp[(size_t)g * B + b];
  h_l[g] = hpre > 0.f ? hpre : 0.f;
  __syncthreads();

  // base[g] = b2[g] + h·W2[g]
  const float4* h4 = (const float4*)h_l;
  const float4* w4 = (const float4*)(W2 + (size_t)g * FEAT);
  {
    float s = b2[g];
    for (int f4 = 0; f4 < FEAT / 4; ++f4) {
      float4 hh = h4[f4], w = w4[f4];
      s += hh.x * w.x + hh.y * w.y + hh.z * w.z + hh.w * w.w;
    }
    base_l[g] = s;
  }
  __syncthreads();

  // mid[hid] = relu(mb1 + base·mW1[hid])   (threads 0..63)
  if (g < HID) {
    float s = mb1[g];
    const float4* b4 = (const float4*)base_l;
    const float4* mw = (const float4*)(mW1 + (size_t)g * FEAT);
    for (int f4 = 0; f4 < FEAT / 4; ++f4) {
      float4 bb = b4[f4], w = mw[f4];
      s += bb.x * w.x + bb.y * w.y + bb.z * w.z + bb.w * w.w;
    }
    mid_l[g] = s > 0.f ? s : 0.f;
  }
  __syncthreads();

  // coefs[t]   (threads 0..3)
  if (g < T) {
    float s = mb2[g];
    const float* wrow = mW2 + g * HID;
    for (int hh = 0; hh < HID; ++hh) s += mid_l[hh] * wrow[hh];
    c_l[g] = s;
  }
  __syncthreads();

  // u[g] = (hpre>0) * sum_t c[t]*dhpre[t][g]
  {
    float s = 0.f;
    if (hpre > 0.f) {
#pragma unroll
      for (int t = 0; t < T; ++t)
        s += c_l[t] * hp[((size_t)(1 + t) * FEAT + g) * B + b];
    }
    u_l[g] = s;
  }
  __syncthreads();

  // out[b][g] = base + sum_t c*db2 + u·W2[g] + sum_t c_t*(h·dW2[t][g])
  float o = base_l[g];
#pragma unroll
  for (int t = 0; t < T; ++t) o += c_l[t] * db2[t * FEAT + g];
  const float4* u4 = (const float4*)u_l;
  float a1 = 0.f;
  float a2[T] = {0.f, 0.f, 0.f, 0.f};
  for (int f4 = 0; f4 < FEAT / 4; ++f4) {
    float4 w = w4[f4], uu = u4[f4], hh = h4[f4];
    a1 += uu.x * w.x + uu.y * w.y + uu.z * w.z + uu.w * w.w;
#pragma unroll
    for (int t = 0; t < T; ++t) {
      float4 dv = ((const float4*)(dW2 + (((size_t)t * FEAT) + g) * FEAT))[f4];
      a2[t] += hh.x * dv.x + hh.y * dv.y + hh.z * dv.z + hh.w * dv.w;
    }
  }
  o += a1;
#pragma unroll
  for (int t = 0; t < T; ++t) o += c_l[t] * a2[t];
  out[b * FEAT + g] = o;
}

extern "C" void kernel_launch(void* const* d_in, const int* in_sizes, int n_in,
                              void* d_out, int out_size, void* d_ws, size_t ws_size,
                              hipStream_t stream) {
  const float* x   = (const float*)d_in[0];
  const float* W1  = (const float*)d_in[1];
  const float* b1  = (const float*)d_in[2];
  const float* W2  = (const float*)d_in[3];
  const float* b2  = (const float*)d_in[4];
  const float* mW1 = (const float*)d_in[5];
  const float* mb1 = (const float*)d_in[6];
  const float* mW2 = (const float*)d_in[7];
  const float* mb2 = (const float*)d_in[8];
  const float* dW1 = (const float*)d_in[9];
  const float* db1 = (const float*)d_in[10];
  const float* dW2 = (const float*)d_in[11];
  const float* db2 = (const float*)d_in[12];
  float* out = (float*)d_out;

  float* ws = (float*)d_ws;
  float* P  = ws;                              // [21][1280][8] = 215040
  float* HP = P + (size_t)KS * NROWS * B;      // [1280][8] = 10240

  stage1<<<dim3(KS, NRB), 256, 0, stream>>>(x, W1, dW1, P);
  stage2<<<40, 256, 0, stream>>>(P, b1, db1, HP);
  stage3<<<B, 256, 0, stream>>>(HP, W2, b2, mW1, mb1, mW2, mb2, dW2, db2, out);
}

// Round 9
// 497.009 us; speedup vs baseline: 1.2872x; 1.2872x over previous
//
#include <hip/hip_runtime.h>

#define D_IN 150528
#define FEAT 256
#define HID 64
#define T 4
#define B 8
#define NROWS 1280            // 5 * 256 rows (W1 + 4x dW1)
#define D4 37632              // D_IN / 4 float4 per row
#define KS 21                 // K splits
#define JSTEPS 28             // 588 / 21 (64-float4 steps per chunk); EVEN
#define RPW 4                 // rows per wave
#define RPB 16                // rows per block (4 waves)
#define NRB 80                // 1280 / 16

// ---------------- stage 1: the 5 batched GEMVs over K=150528 ----------------
// grid (21, 80), block 256 = 4 waves, no LDS/barriers (r7 structure, 241us)
// + register double-buffer on the matrix rows: j+1's 4 HBM row-loads are
// issued BEFORE j's FMA block (2-unrolled loop, named A/B buffers, all
// indices compile-time) so the vmcnt drain overlaps compute. x loads sit
// inside the b-loop (L1-hot, short latency) keeping live regs ~90 -> no spill.
__global__ __launch_bounds__(256, 4) void stage1(
    const float* __restrict__ x, const float* __restrict__ W1,
    const float* __restrict__ dW1, float* __restrict__ partial) {
  const int ks   = blockIdx.x;                        // 0..20
  const int rb   = blockIdx.y;                        // 0..79
  const int wid  = threadIdx.x >> 6;                  // wave 0..3
  const int lane = threadIdx.x & 63;
  const int r0   = rb * RPB + wid * RPW;              // this wave's 4 rows
  const int kb4  = ks * (JSTEPS * 64);                // float4 offset in K

  const float4* rp[RPW];
#pragma unroll
  for (int i = 0; i < RPW; ++i) {
    int r = r0 + i, m = r >> 8, f = r & 255;
    const float* base = (m == 0) ? (W1 + (size_t)f * D_IN)
                                 : (dW1 + ((size_t)(m - 1) * FEAT + f) * D_IN);
    rp[i] = (const float4*)base + kb4;
  }
  const float4* x4 = (const float4*)x + kb4;          // + b*D4 + idx

  float acc[RPW][B];
#pragma unroll
  for (int i = 0; i < RPW; ++i)
#pragma unroll
    for (int b = 0; b < B; ++b) acc[i][b] = 0.f;

  float4 mvA[RPW], mvB[RPW];
#pragma unroll
  for (int i = 0; i < RPW; ++i) mvA[i] = rp[i][lane]; // prologue: j=0

  for (int j = 0; j < JSTEPS; j += 2) {
    const int i1 = (j + 1) * 64 + lane;               // always < 28*64
    const int i2 = ((j + 2 < JSTEPS) ? (j + 2) : 0) * 64 + lane;
    // prefetch j+1 rows, then compute j with mvA
#pragma unroll
    for (int i = 0; i < RPW; ++i) mvB[i] = rp[i][i1];
    {
      const int idx = j * 64 + lane;
#pragma unroll
      for (int b = 0; b < B; ++b) {
        float4 xv = x4[(size_t)b * D4 + idx];         // L1/L2-hot
#pragma unroll
        for (int i = 0; i < RPW; ++i)
          acc[i][b] += mvA[i].x * xv.x + mvA[i].y * xv.y +
                       mvA[i].z * xv.z + mvA[i].w * xv.w;
      }
    }
    // prefetch j+2 rows, then compute j+1 with mvB
#pragma unroll
    for (int i = 0; i < RPW; ++i) mvA[i] = rp[i][i2];
    {
      const int idx = (j + 1) * 64 + lane;
#pragma unroll
      for (int b = 0; b < B; ++b) {
        float4 xv = x4[(size_t)b * D4 + idx];
#pragma unroll
        for (int i = 0; i < RPW; ++i)
          acc[i][b] += mvB[i].x * xv.x + mvB[i].y * xv.y +
                       mvB[i].z * xv.z + mvB[i].w * xv.w;
      }
    }
  }

  // full-wave butterfly per (i,b); lane k (k<32) keeps pair (k>>3, k&7)
  float outv = 0.f;
#pragma unroll
  for (int i = 0; i < RPW; ++i)
#pragma unroll
    for (int b = 0; b < B; ++b) {
      float v = acc[i][b];
      v += __shfl_xor(v, 1);
      v += __shfl_xor(v, 2);
      v += __shfl_xor(v, 4);
      v += __shfl_xor(v, 8);
      v += __shfl_xor(v, 16);
      v += __shfl_xor(v, 32);
      if (lane == i * B + b) outv = v;                // compile-time acc index
    }
  if (lane < RPW * B)                                 // 32 consecutive floats
    partial[((size_t)ks * NROWS + r0) * B + lane] = outv;
}

// ---------------- stage 2: reduce K-splits, add biases ----------------
__global__ __launch_bounds__(256) void stage2(
    const float* __restrict__ partial, const float* __restrict__ b1,
    const float* __restrict__ db1, float* __restrict__ hp) {
  int idx = blockIdx.x * 256 + threadIdx.x;           // 0..10239
  int r = idx >> 3, b = idx & 7;
  int m = r >> 8, f = r & 255;
  float s = (m == 0) ? b1[f] : db1[(m - 1) * FEAT + f];
  for (int ks = 0; ks < KS; ++ks)
    s += partial[((size_t)ks * NROWS + r) * B + b];
  hp[idx] = s;                                        // hp[r][b]
}

// ---------------- stage 3: everything after hpre, one block per batch ------
__global__ __launch_bounds__(256) void stage3(
    const float* __restrict__ hp, const float* __restrict__ W2,
    const float* __restrict__ b2, const float* __restrict__ mW1,
    const float* __restrict__ mb1, const float* __restrict__ mW2,
    const float* __restrict__ mb2, const float* __restrict__ dW2,
    const float* __restrict__ db2, float* __restrict__ out) {
  __shared__ float h_l[FEAT];
  __shared__ float base_l[FEAT];
  __shared__ float u_l[FEAT];
  __shared__ float mid_l[HID];
  __shared__ float c_l[T];
  const int b = blockIdx.x;                           // batch
  const int g = threadIdx.x;                          // feature

  const float hpre = hp[(size_t)g * B + b];
  h_l[g] = hpre > 0.f ? hpre : 0.f;
  __syncthreads();

  // base[g] = b2[g] + h·W2[g]
  const float4* h4 = (const float4*)h_l;
  const float4* w4 = (const float4*)(W2 + (size_t)g * FEAT);
  {
    float s = b2[g];
    for (int f4 = 0; f4 < FEAT / 4; ++f4) {
      float4 hh = h4[f4], w = w4[f4];
      s += hh.x * w.x + hh.y * w.y + hh.z * w.z + hh.w * w.w;
    }
    base_l[g] = s;
  }
  __syncthreads();

  // mid[hid] = relu(mb1 + base·mW1[hid])   (threads 0..63)
  if (g < HID) {
    float s = mb1[g];
    const float4* b4 = (const float4*)base_l;
    const float4* mw = (const float4*)(mW1 + (size_t)g * FEAT);
    for (int f4 = 0; f4 < FEAT / 4; ++f4) {
      float4 bb = b4[f4], w = mw[f4];
      s += bb.x * w.x + bb.y * w.y + bb.z * w.z + bb.w * w.w;
    }
    mid_l[g] = s > 0.f ? s : 0.f;
  }
  __syncthreads();

  // coefs[t]   (threads 0..3)
  if (g < T) {
    float s = mb2[g];
    const float* wrow = mW2 + g * HID;
    for (int hh = 0; hh < HID; ++hh) s += mid_l[hh] * wrow[hh];
    c_l[g] = s;
  }
  __syncthreads();

  // u[g] = (hpre>0) * sum_t c[t]*dhpre[t][g]
  {
    float s = 0.f;
    if (hpre > 0.f) {
#pragma unroll
      for (int t = 0; t < T; ++t)
        s += c_l[t] * hp[((size_t)(1 + t) * FEAT + g) * B + b];
    }
    u_l[g] = s;
  }
  __syncthreads();

  // out[b][g] = base + sum_t c*db2 + u·W2[g] + sum_t c_t*(h·dW2[t][g])
  float o = base_l[g];
#pragma unroll
  for (int t = 0; t < T; ++t) o += c_l[t] * db2[t * FEAT + g];
  const float4* u4 = (const float4*)u_l;
  float a1 = 0.f;
  float a2[T] = {0.f, 0.f, 0.f, 0.f};
  for (int f4 = 0; f4 < FEAT / 4; ++f4) {
    float4 w = w4[f4], uu = u4[f4], hh = h4[f4];
    a1 += uu.x * w.x + uu.y * w.y + uu.z * w.z + uu.w * w.w;
#pragma unroll
    for (int t = 0; t < T; ++t) {
      float4 dv = ((const float4*)(dW2 + (((size_t)t * FEAT) + g) * FEAT))[f4];
      a2[t] += hh.x * dv.x + hh.y * dv.y + hh.z * dv.z + hh.w * dv.w;
    }
  }
  o += a1;
#pragma unroll
  for (int t = 0; t < T; ++t) o += c_l[t] * a2[t];
  out[b * FEAT + g] = o;
}

extern "C" void kernel_launch(void* const* d_in, const int* in_sizes, int n_in,
                              void* d_out, int out_size, void* d_ws, size_t ws_size,
                              hipStream_t stream) {
  const float* x   = (const float*)d_in[0];
  const float* W1  = (const float*)d_in[1];
  const float* b1  = (const float*)d_in[2];
  const float* W2  = (const float*)d_in[3];
  const float* b2  = (const float*)d_in[4];
  const float* mW1 = (const float*)d_in[5];
  const float* mb1 = (const float*)d_in[6];
  const float* mW2 = (const float*)d_in[7];
  const float* mb2 = (const float*)d_in[8];
  const float* dW1 = (const float*)d_in[9];
  const float* db1 = (const float*)d_in[10];
  const float* dW2 = (const float*)d_in[11];
  const float* db2 = (const float*)d_in[12];
  float* out = (float*)d_out;

  float* ws = (float*)d_ws;
  float* P  = ws;                              // [21][1280][8] = 215040
  float* HP = P + (size_t)KS * NROWS * B;      // [1280][8] = 10240

  stage1<<<dim3(KS, NRB), 256, 0, stream>>>(x, W1, dW1, P);
  stage2<<<40, 256, 0, stream>>>(P, b1, db1, HP);
  stage3<<<B, 256, 0, stream>>>(HP, W2, b2, mW1, mb1, mW2, mb2, dW2, db2, out);
}

// Round 10
// 265.059 us; speedup vs baseline: 2.4136x; 1.8751x over previous
//
#include <hip/hip_runtime.h>

#define D_IN 150528
#define FEAT 256
#define HID 64
#define T 4
#define B 8
#define NROWS 1280            // 5 * 256 rows (W1 + 4x dW1)
#define D4 37632              // D_IN / 4 float4 per row
#define KS 21                 // K splits
#define JSTEPS 28             // 588 / 21 (64-float4 steps per chunk)
#define RPW 4                 // rows per wave
#define RPB 16                // rows per block (4 waves)
#define NRB 80                // 1280 / 16

// ---------------- stage 1: the 5 batched GEMVs over K=150528 ----------------
// r7 structure (best: 241us) with ONE change: no min-waves launch_bounds arg.
// (256,4) made hipcc cap at 64 VGPR -> ~35 regs/thread spilled to scratch
// (r9: WRITE_SIZE 396MB vs 1MB of real output). Plain (256) lets it allocate
// ~100 regs: still 4 waves/SIMD (<=128), zero scratch, no scratch-pool cap.
__global__ __launch_bounds__(256) void stage1(
    const float* __restrict__ x, const float* __restrict__ W1,
    const float* __restrict__ dW1, float* __restrict__ partial) {
  const int ks   = blockIdx.x;                        // 0..20
  const int rb   = blockIdx.y;                        // 0..79
  const int wid  = threadIdx.x >> 6;                  // wave 0..3
  const int lane = threadIdx.x & 63;
  const int r0   = rb * RPB + wid * RPW;              // this wave's 4 rows
  const int kb4  = ks * (JSTEPS * 64);                // float4 offset in K

  const float4* rp[RPW];
#pragma unroll
  for (int i = 0; i < RPW; ++i) {
    int r = r0 + i, m = r >> 8, f = r & 255;
    const float* base = (m == 0) ? (W1 + (size_t)f * D_IN)
                                 : (dW1 + ((size_t)(m - 1) * FEAT + f) * D_IN);
    rp[i] = (const float4*)base + kb4;
  }
  const float4* x4 = (const float4*)x + kb4;          // + b*D4 + idx

  float acc[RPW][B];
#pragma unroll
  for (int i = 0; i < RPW; ++i)
#pragma unroll
    for (int b = 0; b < B; ++b) acc[i][b] = 0.f;

  for (int j = 0; j < JSTEPS; ++j) {
    const int idx = j * 64 + lane;
    float4 mv[RPW];
#pragma unroll
    for (int i = 0; i < RPW; ++i) mv[i] = rp[i][idx]; // 4x 1KB HBM streams
    float4 xv[B];
#pragma unroll
    for (int b = 0; b < B; ++b) xv[b] = x4[(size_t)b * D4 + idx]; // L1/L2-hot
#pragma unroll
    for (int b = 0; b < B; ++b)
#pragma unroll
      for (int i = 0; i < RPW; ++i)
        acc[i][b] += mv[i].x * xv[b].x + mv[i].y * xv[b].y +
                     mv[i].z * xv[b].z + mv[i].w * xv[b].w;
  }

  // full-wave butterfly per (i,b); lane k (k<32) keeps pair (k>>3, k&7)
  float outv = 0.f;
#pragma unroll
  for (int i = 0; i < RPW; ++i)
#pragma unroll
    for (int b = 0; b < B; ++b) {
      float v = acc[i][b];
      v += __shfl_xor(v, 1);
      v += __shfl_xor(v, 2);
      v += __shfl_xor(v, 4);
      v += __shfl_xor(v, 8);
      v += __shfl_xor(v, 16);
      v += __shfl_xor(v, 32);
      if (lane == i * B + b) outv = v;                // compile-time acc index
    }
  if (lane < RPW * B)                                 // 32 consecutive floats
    partial[((size_t)ks * NROWS + r0) * B + lane] = outv;
}

// ---------------- stage 2: reduce K-splits, add biases ----------------
__global__ __launch_bounds__(256) void stage2(
    const float* __restrict__ partial, const float* __restrict__ b1,
    const float* __restrict__ db1, float* __restrict__ hp) {
  int idx = blockIdx.x * 256 + threadIdx.x;           // 0..10239
  int r = idx >> 3, b = idx & 7;
  int m = r >> 8, f = r & 255;
  float s = (m == 0) ? b1[f] : db1[(m - 1) * FEAT + f];
  for (int ks = 0; ks < KS; ++ks)
    s += partial[((size_t)ks * NROWS + r) * B + b];
  hp[idx] = s;                                        // hp[r][b]
}

// ---------------- stage 3: everything after hpre, one block per batch ------
__global__ __launch_bounds__(256) void stage3(
    const float* __restrict__ hp, const float* __restrict__ W2,
    const float* __restrict__ b2, const float* __restrict__ mW1,
    const float* __restrict__ mb1, const float* __restrict__ mW2,
    const float* __restrict__ mb2, const float* __restrict__ dW2,
    const float* __restrict__ db2, float* __restrict__ out) {
  __shared__ float h_l[FEAT];
  __shared__ float base_l[FEAT];
  __shared__ float u_l[FEAT];
  __shared__ float mid_l[HID];
  __shared__ float c_l[T];
  const int b = blockIdx.x;                           // batch
  const int g = threadIdx.x;                          // feature

  const float hpre = hp[(size_t)g * B + b];
  h_l[g] = hpre > 0.f ? hpre : 0.f;
  __syncthreads();

  // base[g] = b2[g] + h·W2[g]
  const float4* h4 = (const float4*)h_l;
  const float4* w4 = (const float4*)(W2 + (size_t)g * FEAT);
  {
    float s = b2[g];
    for (int f4 = 0; f4 < FEAT / 4; ++f4) {
      float4 hh = h4[f4], w = w4[f4];
      s += hh.x * w.x + hh.y * w.y + hh.z * w.z + hh.w * w.w;
    }
    base_l[g] = s;
  }
  __syncthreads();

  // mid[hid] = relu(mb1 + base·mW1[hid])   (threads 0..63)
  if (g < HID) {
    float s = mb1[g];
    const float4* b4 = (const float4*)base_l;
    const float4* mw = (const float4*)(mW1 + (size_t)g * FEAT);
    for (int f4 = 0; f4 < FEAT / 4; ++f4) {
      float4 bb = b4[f4], w = mw[f4];
      s += bb.x * w.x + bb.y * w.y + bb.z * w.z + bb.w * w.w;
    }
    mid_l[g] = s > 0.f ? s : 0.f;
  }
  __syncthreads();

  // coefs[t]   (threads 0..3)
  if (g < T) {
    float s = mb2[g];
    const float* wrow = mW2 + g * HID;
    for (int hh = 0; hh < HID; ++hh) s += mid_l[hh] * wrow[hh];
    c_l[g] = s;
  }
  __syncthreads();

  // u[g] = (hpre>0) * sum_t c[t]*dhpre[t][g]
  {
    float s = 0.f;
    if (hpre > 0.f) {
#pragma unroll
      for (int t = 0; t < T; ++t)
        s += c_l[t] * hp[((size_t)(1 + t) * FEAT + g) * B + b];
    }
    u_l[g] = s;
  }
  __syncthreads();

  // out[b][g] = base + sum_t c*db2 + u·W2[g] + sum_t c_t*(h·dW2[t][g])
  float o = base_l[g];
#pragma unroll
  for (int t = 0; t < T; ++t) o += c_l[t] * db2[t * FEAT + g];
  const float4* u4 = (const float4*)u_l;
  float a1 = 0.f;
  float a2[T] = {0.f, 0.f, 0.f, 0.f};
  for (int f4 = 0; f4 < FEAT / 4; ++f4) {
    float4 w = w4[f4], uu = u4[f4], hh = h4[f4];
    a1 += uu.x * w.x + uu.y * w.y + uu.z * w.z + uu.w * w.w;
#pragma unroll
    for (int t = 0; t < T; ++t) {
      float4 dv = ((const float4*)(dW2 + (((size_t)t * FEAT) + g) * FEAT))[f4];
      a2[t] += hh.x * dv.x + hh.y * dv.y + hh.z * dv.z + hh.w * dv.w;
    }
  }
  o += a1;
#pragma unroll
  for (int t = 0; t < T; ++t) o += c_l[t] * a2[t];
  out[b * FEAT + g] = o;
}

extern "C" void kernel_launch(void* const* d_in, const int* in_sizes, int n_in,
                              void* d_out, int out_size, void* d_ws, size_t ws_size,
                              hipStream_t stream) {
  const float* x   = (const float*)d_in[0];
  const float* W1  = (const float*)d_in[1];
  const float* b1  = (const float*)d_in[2];
  const float* W2  = (const float*)d_in[3];
  const float* b2  = (const float*)d_in[4];
  const float* mW1 = (const float*)d_in[5];
  const float* mb1 = (const float*)d_in[6];
  const float* mW2 = (const float*)d_in[7];
  const float* mb2 = (const float*)d_in[8];
  const float* dW1 = (const float*)d_in[9];
  const float* db1 = (const float*)d_in[10];
  const float* dW2 = (const float*)d_in[11];
  const float* db2 = (const float*)d_in[12];
  float* out = (float*)d_out;

  float* ws = (float*)d_ws;
  float* P  = ws;                              // [21][1280][8] = 215040
  float* HP = P + (size_t)KS * NROWS * B;      // [1280][8] = 10240

  stage1<<<dim3(KS, NRB), 256, 0, stream>>>(x, W1, dW1, P);
  stage2<<<40, 256, 0, stream>>>(P, b1, db1, HP);
  stage3<<<B, 256, 0, stream>>>(HP, W2, b2, mW1, mb1, mW2, mb2, dW2, db2, out);
}